// Round 6
// baseline (3572.297 us; speedup 1.0000x reference)
//
#include <hip/hip_runtime.h>

using short8 = __attribute__((ext_vector_type(8))) short;
using f32x16 = __attribute__((ext_vector_type(16))) float;

typedef unsigned short u16;
typedef unsigned int   u32;

#define T_SEQ 256
#define BATCH 64
#define INP   256
#define HID   1024
#define GDIM  4096
#define KC    1280   // HID + INP
#define OUTD  1024
#define NBLK  256
#define DBLK  128    // blocks per direction

#define MFMA32(a,b,c) __builtin_amdgcn_mfma_f32_32x32x16_bf16(a,b,c,0,0,0)

__device__ __forceinline__ u16 f2bf(float f){
  union { float f; u32 u; } v; v.f = f;
  u32 r = v.u + 0x7fffu + ((v.u >> 16) & 1u);
  return (u16)(r >> 16);
}
__device__ __forceinline__ float sigm(float x){ return 1.f/(1.f+__expf(-x)); }
__device__ __forceinline__ float tanhf_(float x){ return 1.f - 2.f/(__expf(2.f*x)+1.f); }

// write-through (coherent) stores: visible at IC, never dirty remote L2
__device__ __forceinline__ void st_u32_wt(u32* p, u32 v){
  asm volatile("global_store_dword %0, %1, off sc0 sc1" :: "v"(p), "v"(v) : "memory");
}
__device__ __forceinline__ void st_f32_wt(float* p, float v){
  asm volatile("global_store_dword %0, %1, off sc0 sc1" :: "v"(p), "v"(v) : "memory");
}

// quad-perm DPP (xor patterns are direction-proof)
template<int CTRL>
__device__ __forceinline__ float qperm(float v){
  union { float f; int i; } u; u.f = v;
  u.i = __builtin_amdgcn_mov_dpp(u.i, CTRL, 0xf, 0xf, true);
  return u.f;
}
#define QP_XOR1 177   // quad_perm [1,0,3,2]
#define QP_XOR2 78    // quad_perm [2,3,0,1]

// ---------------------------------------------------------------------------
// Prep: combined recurrent weights, bf16.  Block nb owns gate-cols
// [nb*32, nb*32+32) with local order n = nb*32 + (j&7)*4 + gate
// (h-col j = nb*8 + (local>>2), gate = local&3 -> DPP quad = one h-col).
// Rows: k<1024 -> Wh[k][gate*1024+j], k>=1024 -> Wx[k-1024][gate*1024+j].
// ---------------------------------------------------------------------------
__global__ void build_wc(const float* __restrict__ WhF, const float* __restrict__ WxF,
                         const float* __restrict__ WhB, const float* __restrict__ WxB,
                         u16* __restrict__ WcF, u16* __restrict__ WcB)
{
  const int z = blockIdx.z; const int dir = z >> 2, gate = z & 3;
  const float* Wh = dir ? WhB : WhF;
  const float* Wx = dir ? WxB : WxF;
  u16* Wc = dir ? WcB : WcF;
  const int k0 = blockIdx.x * 64, j0 = blockIdx.y * 64;
  __shared__ float tile[64][65];
  const int t = threadIdx.x;
  #pragma unroll
  for (int i = 0; i < 16; ++i) {
    int idx = i*256 + t; int kr = idx >> 6, jc = idx & 63;
    int k = k0 + kr;
    float v = (k < HID) ? Wh[(size_t)k*GDIM + gate*HID + j0 + jc]
                        : Wx[(size_t)(k-HID)*GDIM + gate*HID + j0 + jc];
    tile[kr][jc] = v;
  }
  __syncthreads();
  #pragma unroll
  for (int i = 0; i < 16; ++i) {
    int idx = i*256 + t; int jc = idx >> 6, kr = idx & 63;
    int j  = j0 + jc;
    int n  = (j >> 3)*32 + (j & 7)*4 + gate;
    Wc[(size_t)n*KC + k0 + kr] = f2bf(tile[kr][jc]);
  }
}

__global__ void build_wfc(const float* __restrict__ Wfc, u16* __restrict__ WfcT)
{
  const int k0 = blockIdx.x * 64;
  const int n0 = blockIdx.y * 64;
  __shared__ float tile[64][65];
  const int t = threadIdx.x;
  #pragma unroll
  for (int i = 0; i < 16; ++i) {
    int idx = i*256 + t; int kr = idx >> 6, nc = idx & 63;
    tile[kr][nc] = Wfc[(size_t)(k0+kr)*OUTD + n0 + nc];
  }
  __syncthreads();
  #pragma unroll
  for (int i = 0; i < 16; ++i) {
    int idx = i*256 + t; int nc = idx >> 6, kr = idx & 63;
    WfcT[(size_t)(n0+nc)*2048 + k0 + kr] = f2bf(tile[kr][nc]);
  }
}

__global__ void conv_x(const float* __restrict__ x, u16* __restrict__ xb, int n)
{
  int i = (blockIdx.x * blockDim.x + threadIdx.x) * 4;
  if (i < n) {
    float4 v = *(const float4*)(x + i);
    u32 lo = (u32)f2bf(v.x) | ((u32)f2bf(v.y) << 16);
    u32 hi = (u32)f2bf(v.z) | ((u32)f2bf(v.w) << 16);
    *(uint2*)(xb + i) = make_uint2(lo, hi);
  }
}

// ---------------------------------------------------------------------------
// Persistent bidirectional LSTM, 32x32x16 MFMA.
// 256 blocks (128/dir), 4 waves: (bh = batch half) x (kh = K half).
// Each wave's B panel (40 slices of K=16) lives ENTIRELY in VGPRs (160).
// K-halves combined via 16KB LDS; both waves update 8 rows each.
// Per-step sync: write-through h stores + flag array + flag-gated loads.
// ---------------------------------------------------------------------------
__global__ __launch_bounds__(256, 1) void lstm_persist(
    const u16* __restrict__ WcF, const u16* __restrict__ WcB,
    const u16* __restrict__ xb,
    const float* __restrict__ bF, const float* __restrict__ bB,
    u16* __restrict__ hs, float* __restrict__ out_tail, int* flags)
{
  __shared__ float red[4][16][64];
  __builtin_amdgcn_fence(__ATOMIC_ACQUIRE, "agent");

  const int bid = blockIdx.x;
  const int dir = bid >> 7;
  const int nb  = bid & 127;
  const int n0  = nb * 32;
  const int jbase = nb * 8;
  const u16* __restrict__ Wc = dir ? WcB : WcF;
  const float* __restrict__ bias = dir ? bB : bF;
  int* __restrict__ fl = flags + dir * DBLK;

  const int tid = threadIdx.x;
  const int w = tid >> 6, lane = tid & 63;
  const int kh = w & 1, bh = w >> 1;
  const int c5 = lane & 31, hi = lane >> 5;
  const int row = bh * 32 + c5;          // A row this lane reads
  const int sbase = kh ? 32 : 0;         // first h K-slice of this wave
  const int j = jbase + (c5 >> 2);       // h-col of this lane's quad

  // B panel in registers: breg[0..31] = h slices, breg[32..47] = x (kh=1)
  short8 breg[48];
  {
    const u16* wb = Wc + (size_t)(n0 + c5) * KC + hi * 8;
    #pragma unroll
    for (int i = 0; i < 32; ++i) breg[i] = *(const short8*)(wb + (sbase + i) * 16);
    if (kh) {
      #pragma unroll
      for (int i = 0; i < 16; ++i) breg[32 + i] = *(const short8*)(wb + (64 + i) * 16);
    }
  }

  float bia[4];
  #pragma unroll
  for (int g = 0; g < 4; ++g) bia[g] = bias[g * HID + j];

  float creg[8];
  #pragma unroll
  for (int i = 0; i < 8; ++i) creg[i] = 0.f;

  f32x16 acc;
  #pragma unroll
  for (int i = 0; i < 16; ++i) acc[i] = 0.f;

  // x-part of the first timestep (kh=1 waves own the x K-range)
  if (kh) {
    const int tt0 = dir ? T_SEQ - 1 : 0;
    const u16* xr = xb + ((size_t)tt0 * BATCH + row) * INP + hi * 8;
    short8 xf[16];
    #pragma unroll
    for (int i = 0; i < 16; ++i) xf[i] = *(const short8*)(xr + i * 16);
    #pragma unroll
    for (int i = 0; i < 16; ++i) acc = MFMA32(xf[i], breg[32 + i], acc);
  }

  const int ioff = kh * 8;               // acc regs this wave finalizes

  for (int s = 0; s < T_SEQ; ++s) {
    const int tt = dir ? (T_SEQ - 1 - s) : s;

    if (s > 0) {
      const int tp = dir ? tt + 1 : tt - 1;
      const u16* ar = hs + ((size_t)tp * BATCH + row) * 2048 + dir * HID + sbase * 16 + hi * 8;
      short8 A0[8], A1[8];
      #pragma unroll
      for (int i = 0; i < 8; ++i) A0[i] = *(const short8*)(ar + i * 16);
      #pragma unroll
      for (int i = 0; i < 8; ++i) A1[i] = *(const short8*)(ar + (8 + i) * 16);
      #pragma unroll
      for (int i = 0; i < 8; ++i) acc = MFMA32(A0[i], breg[i], acc);
      #pragma unroll
      for (int i = 0; i < 8; ++i) A0[i] = *(const short8*)(ar + (16 + i) * 16);
      #pragma unroll
      for (int i = 0; i < 8; ++i) acc = MFMA32(A1[i], breg[8 + i], acc);
      #pragma unroll
      for (int i = 0; i < 8; ++i) A1[i] = *(const short8*)(ar + (24 + i) * 16);
      #pragma unroll
      for (int i = 0; i < 8; ++i) acc = MFMA32(A0[i], breg[16 + i], acc);
      #pragma unroll
      for (int i = 0; i < 8; ++i) acc = MFMA32(A1[i], breg[24 + i], acc);
    }

    // cross-K reduction: write all 16 partials, read partner's half
    #pragma unroll
    for (int i = 0; i < 16; ++i) red[w][i][lane] = acc[i];
    __syncthreads();
    float g8[8];
    #pragma unroll
    for (int i = 0; i < 8; ++i) g8[i] = acc[ioff + i] + red[w ^ 1][ioff + i][lane];
    #pragma unroll
    for (int i = 0; i < 16; ++i) acc[i] = 0.f;

    // cell update (all lanes compute their quad's h-col; gate = lane&3 order)
    float hnv[8]; u32 hbv[8];
    #pragma unroll
    for (int i = 0; i < 8; ++i) {
      float v  = g8[i];
      float x1 = qperm<QP_XOR1>(v);
      float x2 = qperm<QP_XOR2>(v);
      float x3 = qperm<QP_XOR2>(x1);
      float cn = sigm(x1 + bia[1]) * creg[i] + sigm(v + bia[0]) * tanhf_(x3 + bia[3]);
      float hn = sigm(x2 + bia[2]) * tanhf_(cn);
      creg[i] = cn; hnv[i] = hn; hbv[i] = (u32)f2bf(hn);
    }

    // pack col pair (j, j+1) via lane^4 swizzle, u32 write-through stores
    {
      u16* hrow = hs + (size_t)tt * BATCH * 2048 + dir * HID + j;
      #pragma unroll
      for (int i = 0; i < 8; ++i) {
        u32 other = (u32)__builtin_amdgcn_ds_swizzle((int)hbv[i], 0x101F); // lane^4
        if ((lane & 7) == 0) {
          int ri = (i & 3) + 8 * (i >> 2) + 16 * kh + 4 * hi + 32 * bh;
          st_u32_wt((u32*)(hrow + (size_t)ri * 2048), hbv[i] | (other << 16));
        }
      }
    }

    if (s < T_SEQ - 1) {
      asm volatile("s_waitcnt vmcnt(0)" ::: "memory");  // drain h stores to IC
      // issue next-step x loads now; they land during the barrier
      short8 xf[16];
      if (kh) {
        const int tn = dir ? tt - 1 : tt + 1;
        const u16* xr = xb + ((size_t)tn * BATCH + row) * INP + hi * 8;
        #pragma unroll
        for (int i = 0; i < 16; ++i) xf[i] = *(const short8*)(xr + i * 16);
      }
      __syncthreads();
      if (tid == 0) st_u32_wt((u32*)(fl + nb), (u32)(s + 1));
      if (w == 0) {
        const int tgt = s + 1;
        while (true) {
          int f0 = __hip_atomic_load(fl + 2 * lane,     __ATOMIC_RELAXED, __HIP_MEMORY_SCOPE_AGENT);
          int f1 = __hip_atomic_load(fl + 2 * lane + 1, __ATOMIC_RELAXED, __HIP_MEMORY_SCOPE_AGENT);
          if (__all((f0 >= tgt) && (f1 >= tgt))) break;
        }
      }
      __syncthreads();   // hs addresses are write-once; loads are flag-gated
      if (kh) {
        #pragma unroll
        for (int i = 0; i < 16; ++i) acc = MFMA32(xf[i], breg[32 + i], acc);
      }
    } else {
      // final states (writers: one lane per h-col quad)
      if ((lane & 3) == 0) {
        float* ot = out_tail + dir * (BATCH * HID);
        #pragma unroll
        for (int i = 0; i < 8; ++i) {
          int ri = (i & 3) + 8 * (i >> 2) + 16 * kh + 4 * hi + 32 * bh;
          st_f32_wt(ot + (size_t)ri * HID + j, hnv[i]);
          st_f32_wt(ot + 2 * (BATCH * HID) + (size_t)ri * HID + j, creg[i]);
        }
      }
    }
  }
}

// ---------------------------------------------------------------------------
// Final FC: out[16384][1024] = hs[16384][2048] @ WfcT^T + b_fc, f32 out.
// ---------------------------------------------------------------------------
using f32x4 = __attribute__((ext_vector_type(4))) float;

__global__ __launch_bounds__(256) void fc_kernel(
    const u16* __restrict__ hs, const u16* __restrict__ WfcT,
    const float* __restrict__ bfc, float* __restrict__ out)
{
  const int m0 = blockIdx.x * 128, n0 = blockIdx.y * 128;
  __shared__ __align__(16) u16 As[128 * 32];
  __shared__ __align__(16) u16 Bs[128 * 32];
  const int tid = threadIdx.x;
  const int w = tid >> 6, lane = tid & 63;
  const int r = lane & 15, q = lane >> 4;
  const int wy = w >> 1, wx = w & 1;

  f32x4 acc[4][4];
  #pragma unroll
  for (int a = 0; a < 4; ++a)
    #pragma unroll
    for (int b = 0; b < 4; ++b) acc[a][b] = (f32x4)(0.f);

  const int lr = tid >> 1, lk = (tid & 1) * 16;

  for (int k0 = 0; k0 < 2048; k0 += 32) {
    __syncthreads();
    *(short8*)&As[lr * 32 + lk]     = *(const short8*)(hs   + (size_t)(m0 + lr) * 2048 + k0 + lk);
    *(short8*)&As[lr * 32 + lk + 8] = *(const short8*)(hs   + (size_t)(m0 + lr) * 2048 + k0 + lk + 8);
    *(short8*)&Bs[lr * 32 + lk]     = *(const short8*)(WfcT + (size_t)(n0 + lr) * 2048 + k0 + lk);
    *(short8*)&Bs[lr * 32 + lk + 8] = *(const short8*)(WfcT + (size_t)(n0 + lr) * 2048 + k0 + lk + 8);
    __syncthreads();

    short8 af[4], bf[4];
    #pragma unroll
    for (int mt = 0; mt < 4; ++mt)
      af[mt] = *(const short8*)&As[(wy * 64 + mt * 16 + r) * 32 + q * 8];
    #pragma unroll
    for (int nt = 0; nt < 4; ++nt)
      bf[nt] = *(const short8*)&Bs[(wx * 64 + nt * 16 + r) * 32 + q * 8];
    #pragma unroll
    for (int mt = 0; mt < 4; ++mt)
      #pragma unroll
      for (int nt = 0; nt < 4; ++nt)
        acc[mt][nt] = __builtin_amdgcn_mfma_f32_16x16x32_bf16(af[mt], bf[nt], acc[mt][nt], 0, 0, 0);
  }

  #pragma unroll
  for (int mt = 0; mt < 4; ++mt)
    #pragma unroll
    for (int nt = 0; nt < 4; ++nt)
      #pragma unroll
      for (int reg = 0; reg < 4; ++reg) {
        int m = m0 + wy * 64 + mt * 16 + q * 4 + reg;
        int n = n0 + wx * 64 + nt * 16 + r;
        out[(size_t)m * OUTD + n] = acc[mt][nt][reg] + bfc[n];
      }
}

// ---------------------------------------------------------------------------
extern "C" void kernel_launch(void* const* d_in, const int* in_sizes, int n_in,
                              void* d_out, int out_size, void* d_ws, size_t ws_size,
                              hipStream_t stream)
{
  const float* x   = (const float*)d_in[0];
  const float* WxF = (const float*)d_in[1];
  const float* WhF = (const float*)d_in[2];
  const float* bF  = (const float*)d_in[3];
  const float* WxB = (const float*)d_in[4];
  const float* WhB = (const float*)d_in[5];
  const float* bB  = (const float*)d_in[6];
  const float* Wfc = (const float*)d_in[7];
  const float* bfc = (const float*)d_in[8];
  float* out = (float*)d_out;

  char* ws = (char*)d_ws;
  u16*  WcF   = (u16*)(ws + 0);          // 10485760
  u16*  WcB   = (u16*)(ws + 10485760);   // 10485760
  u16*  WfcT  = (u16*)(ws + 20971520);   // 4194304
  u16*  xb    = (u16*)(ws + 25165824);   // 8388608
  u16*  hs    = (u16*)(ws + 34603008);   // 67108864
  int*  flags = (int*)(ws + 101711872);  // 1KB (256 ints)

  hipMemsetAsync(flags, 0, 1024, stream);   // barrier flags

  build_wc <<<dim3(KC/64, HID/64, 8), 256, 0, stream>>>(WhF, WxF, WhB, WxB, WcF, WcB);
  build_wfc<<<dim3(2048/64, OUTD/64), 256, 0, stream>>>(Wfc, WfcT);
  conv_x   <<<(T_SEQ*BATCH*INP)/4/256, 256, 0, stream>>>(x, xb, T_SEQ*BATCH*INP);

  lstm_persist<<<NBLK, 256, 0, stream>>>(WcF, WcB, xb, bF, bB,
                                         hs, out + 16777216, flags);

  fc_kernel<<<dim3(16384/128, OUTD/128), 256, 0, stream>>>(hs, WfcT, bfc, out);
}